// Round 1
// baseline (19992.059 us; speedup 1.0000x reference)
//
#include <hip/hip_runtime.h>
#include <stdint.h>

#define T_DIM 2048
#define B_DIM 64
#define IDIM_ 1024
#define HDIM_ 1024
#define ODIM_ 512

typedef short s8v __attribute__((ext_vector_type(8)));
typedef float f4v __attribute__((ext_vector_type(4)));

__device__ __forceinline__ float bf2f(unsigned short u) {
  union { unsigned int i; float f; } v; v.i = ((unsigned int)u) << 16; return v.f;
}
__device__ __forceinline__ unsigned short f2bf(float f) {
  union { float f; unsigned int i; } v; v.f = f;
  unsigned int u = v.i;
  return (unsigned short)((u + 0x7FFFu + ((u >> 16) & 1u)) >> 16);  // RNE, inputs are finite
}
__device__ __forceinline__ unsigned int pack2(float lo, float hi) {
  return (unsigned int)f2bf(lo) | ((unsigned int)f2bf(hi) << 16);
}

// ---------------------------------------------------------------- weights fp32 -> bf16
__global__ void cvt_weights(const float* __restrict__ wih, const float* __restrict__ whh,
                            unsigned short* __restrict__ wihb, unsigned short* __restrict__ whhb) {
  int idx = blockIdx.x * blockDim.x + threadIdx.x;
  int stride = gridDim.x * blockDim.x;
  const int n4 = (HDIM_ * IDIM_) / 4;
  for (int i = idx; i < n4; i += stride) {
    float4 a = ((const float4*)wih)[i];
    float4 b = ((const float4*)whh)[i];
    uint2 ra = { pack2(a.x, a.y), pack2(a.z, a.w) };
    uint2 rb = { pack2(b.x, b.y), pack2(b.z, b.w) };
    ((uint2*)wihb)[i] = ra;
    ((uint2*)whhb)[i] = rb;
  }
}

// ---------------------------------------------------------------- phase 1: A = X @ Wih^T + bh
// X: [131072][1024] fp32 (row m = b*2048 + t), Wb: [1024][1024] bf16, A out: [131072][1024] bf16
__global__ __launch_bounds__(256) void xproj_gemm(
    const float* __restrict__ X, const unsigned short* __restrict__ Wb,
    const float* __restrict__ bh, unsigned short* __restrict__ A) {
  __shared__ unsigned short Xs[128][40];   // 32 valid k + 8 pad (bank-conflict break)
  __shared__ unsigned short Wls[128][40];

  const int tid = threadIdx.x;
  const int bid = blockIdx.x;
  const int mt = bid >> 3, nt = bid & 7;       // consecutive bids share the X m-tile (L3 reuse)
  const size_t mbase = (size_t)mt * 128;
  const int nbase = nt * 128;

  const int wave = tid >> 6, lane = tid & 63;
  const int row16 = lane & 15, quad = lane >> 4;
  const int wm = wave >> 1, wn = wave & 1;

  f4v acc[4][4];
#pragma unroll
  for (int i = 0; i < 4; ++i)
#pragma unroll
    for (int j = 0; j < 4; ++j) acc[i][j] = (f4v){0.f, 0.f, 0.f, 0.f};

  const int r_st = tid >> 1, half = tid & 1;

  for (int k0 = 0; k0 < IDIM_; k0 += 32) {
    // stage X (fp32 -> bf16)
    {
      const float* src = X + (mbase + r_st) * IDIM_ + k0 + half * 16;
      float4 f0 = ((const float4*)src)[0];
      float4 f1 = ((const float4*)src)[1];
      float4 f2 = ((const float4*)src)[2];
      float4 f3 = ((const float4*)src)[3];
      uint4 w0 = { pack2(f0.x,f0.y), pack2(f0.z,f0.w), pack2(f1.x,f1.y), pack2(f1.z,f1.w) };
      uint4 w1 = { pack2(f2.x,f2.y), pack2(f2.z,f2.w), pack2(f3.x,f3.y), pack2(f3.z,f3.w) };
      *(uint4*)&Xs[r_st][half * 16] = w0;
      *(uint4*)&Xs[r_st][half * 16 + 8] = w1;
    }
    // stage W slice (already bf16)
    if (tid < 128) {
      const uint4* src = (const uint4*)(Wb + (size_t)(nbase + tid) * IDIM_ + k0);
      uint4 w0 = src[0], w1 = src[1], w2 = src[2], w3 = src[3];
      *(uint4*)&Wls[tid][0]  = w0;
      *(uint4*)&Wls[tid][8]  = w1;
      *(uint4*)&Wls[tid][16] = w2;
      *(uint4*)&Wls[tid][24] = w3;
    }
    __syncthreads();
    s8v a[4], b[4];
#pragma unroll
    for (int i = 0; i < 4; ++i) a[i] = *(const s8v*)&Xs[64 * wm + 16 * i + row16][quad * 8];
#pragma unroll
    for (int j = 0; j < 4; ++j) b[j] = *(const s8v*)&Wls[64 * wn + 16 * j + row16][quad * 8];
#pragma unroll
    for (int i = 0; i < 4; ++i)
#pragma unroll
      for (int j = 0; j < 4; ++j)
        acc[i][j] = __builtin_amdgcn_mfma_f32_16x16x32_bf16(a[i], b[j], acc[i][j], 0, 0, 0);
    __syncthreads();
  }
  // epilogue: + bh, store bf16
#pragma unroll
  for (int j = 0; j < 4; ++j) {
    int n = nbase + 64 * wn + 16 * j + row16;
    float bias = bh[n];
#pragma unroll
    for (int i = 0; i < 4; ++i) {
      size_t m0 = mbase + 64 * wm + 16 * i + quad * 4;
#pragma unroll
      for (int r = 0; r < 4; ++r)
        A[(m0 + r) * HDIM_ + n] = f2bf(acc[i][j][r] + bias);
    }
  }
}

// ---------------------------------------------------------------- device-scope barrier
__device__ __forceinline__ void gbar(unsigned int* ctr, unsigned int goal) {
  __syncthreads();
  if (threadIdx.x == 0) {
    __builtin_amdgcn_fence(__ATOMIC_RELEASE, "agent");   // L2 writeback: h slice visible in L3
    __hip_atomic_fetch_add(ctr, 1u, __ATOMIC_RELAXED, __HIP_MEMORY_SCOPE_AGENT);
    while (__hip_atomic_load(ctr, __ATOMIC_RELAXED, __HIP_MEMORY_SCOPE_AGENT) < goal) {}
    __builtin_amdgcn_fence(__ATOMIC_ACQUIRE, "agent");   // L1/L2 invalidate: fresh h next step
  }
  __syncthreads();
}

// ---------------------------------------------------------------- phase 2: persistent recurrence
// 64 blocks x 256 threads; block g owns h columns [g*16, g*16+16)
__global__ __launch_bounds__(256, 1) void rnn_persist(
    const unsigned short* __restrict__ A,    // [131072][1024] bf16, row m = b*2048+t
    const unsigned short* __restrict__ Whh,  // [1024][1024] bf16
    const float* __restrict__ Wout,          // [512][1024] fp32
    const float* __restrict__ bout,          // [512]
    unsigned short* __restrict__ h0, unsigned short* __restrict__ h1,
    unsigned int* ctr, float* __restrict__ out) {
  const int g = blockIdx.x;
  const int tid = threadIdx.x;
  const int wave = tid >> 6, lane = tid & 63;
  const int row16 = lane & 15, quad = lane >> 4;
  const int n0 = g * 16;

  // W_hh column-slice in registers, MFMA B-frag layout: lane holds col=row16, k=quad*8+j
  s8v wreg[32];
  {
    const unsigned short* wrow = Whh + (size_t)(n0 + row16) * HDIM_ + quad * 8;
#pragma unroll
    for (int kk = 0; kk < 32; ++kk) wreg[kk] = *(const s8v*)(wrow + (size_t)kk * 32);
  }

  // zero this block's h0 slice (contiguous 1024 elems)
  for (int i = tid; i < 1024; i += 256) h0[g * 1024 + i] = 0;
  gbar(ctr, 64u);  // all zeros visible before t=0

  for (int t = 0; t < T_DIM; ++t) {
    const unsigned short* hp = (t & 1) ? h1 : h0;
    unsigned short* hn = (t & 1) ? h0 : h1;

    // prefetch A values (independent of h) — overlap with h-load latency
    const int bb = 16 * wave + quad * 4;
    float aval[4];
#pragma unroll
    for (int r = 0; r < 4; ++r)
      aval[r] = bf2f(A[((size_t)(bb + r) * T_DIM + t) * HDIM_ + n0 + row16]);

    f4v acc0 = (f4v){0.f, 0.f, 0.f, 0.f};
    f4v acc1 = (f4v){0.f, 0.f, 0.f, 0.f};
    const unsigned short* hrow = hp + (size_t)(16 * wave + row16) * HDIM_ + quad * 8;
#pragma unroll
    for (int kk = 0; kk < 32; kk += 2) {
      s8v a0 = *(const s8v*)(hrow + (size_t)kk * 32);
      s8v a1 = *(const s8v*)(hrow + (size_t)(kk + 1) * 32);
      acc0 = __builtin_amdgcn_mfma_f32_16x16x32_bf16(a0, wreg[kk], acc0, 0, 0, 0);
      acc1 = __builtin_amdgcn_mfma_f32_16x16x32_bf16(a1, wreg[kk + 1], acc1, 0, 0, 0);
    }
#pragma unroll
    for (int r = 0; r < 4; ++r) {
      float v = tanhf(acc0[r] + acc1[r] + aval[r]);
      hn[(size_t)(bb + r) * HDIM_ + n0 + row16] = f2bf(v);
    }
    gbar(ctr, 64u * (t + 2));
  }

  // t=2047 (odd) wrote h0 -> final hidden state. Output: block g owns out cols [g*8, g*8+8)
  for (int idx = tid; idx < B_DIM * 8; idx += 256) {
    int b = idx >> 3;
    int o = g * 8 + (idx & 7);
    const unsigned short* hr = h0 + (size_t)b * HDIM_;
    const float* wr = Wout + (size_t)o * HDIM_;
    float s = 0.f;
    for (int k = 0; k < HDIM_; k += 4) {
      float4 w = *(const float4*)(wr + k);
      s += bf2f(hr[k]) * w.x + bf2f(hr[k + 1]) * w.y + bf2f(hr[k + 2]) * w.z + bf2f(hr[k + 3]) * w.w;
    }
    out[b * ODIM_ + o] = s + bout[o];
  }
}

// ---------------------------------------------------------------- launch
extern "C" void kernel_launch(void* const* d_in, const int* in_sizes, int n_in,
                              void* d_out, int out_size, void* d_ws, size_t ws_size,
                              hipStream_t stream) {
  const float* x    = (const float*)d_in[0];
  const float* Wih  = (const float*)d_in[1];
  const float* Whh  = (const float*)d_in[2];
  const float* bh   = (const float*)d_in[3];
  const float* Wout = (const float*)d_in[4];
  const float* bout = (const float*)d_in[5];
  float* out = (float*)d_out;

  char* ws = (char*)d_ws;
  // layout: A 256MiB | WihB 2MiB | WhhB 2MiB | h0 128KiB | h1 128KiB | ctr
  unsigned short* A    = (unsigned short*)ws;
  unsigned short* WihB = (unsigned short*)(ws + (size_t)268435456);
  unsigned short* WhhB = (unsigned short*)(ws + (size_t)268435456 + 2097152);
  unsigned short* h0   = (unsigned short*)(ws + (size_t)268435456 + 2 * 2097152);
  unsigned short* h1   = h0 + 65536;
  unsigned int*   ctr  = (unsigned int*)(h1 + 65536);

  hipMemsetAsync(ctr, 0, 4, stream);
  cvt_weights<<<256, 256, 0, stream>>>(Wih, Whh, WihB, WhhB);
  xproj_gemm<<<8192, 256, 0, stream>>>(x, WihB, bh, A);
  rnn_persist<<<64, 256, 0, stream>>>(A, WhhB, Wout, bout, h0, h1, ctr, out);
}